// Round 16
// baseline (141.766 us; speedup 1.0000x reference)
//
#include <hip/hip_runtime.h>
#include <hip/hip_bf16.h>

#define N_NODES 100000
#define N_EDGES 3200000
#define IN_CH 128
#define HID 16
#define OUT_CH 64
#define BSHIFT 9
#define BNODES 512              // nodes per bucket
#define NBUCK 196               // ceil(100000/512)
#define NREP 8                  // cursor/region replicas (~ per-XCD under round-robin dispatch)
#define BCAPR 2304              // per-(bucket,replica) colp capacity (mean 2048 + ~5.7 sigma)
#define BCAPB (NREP * BCAPR)    // 18432 col words per bucket
#define TR 32                   // gemm1 rows per block
#define XP 132                  // padded LDS row stride (keeps 16B align)
#define EPB 4096                // k_bucket edges per block

__device__ __forceinline__ unsigned short f2bf(float f) {
    union { float f; unsigned v; } t; t.f = f;
    unsigned r = t.v + 0x7FFFu + ((t.v >> 16) & 1u);   // round-to-nearest-even
    return (unsigned short)(r >> 16);
}
__device__ __forceinline__ unsigned pack2(float lo, float hi) {
    return (unsigned)f2bf(lo) | ((unsigned)f2bf(hi) << 16);
}
// accumulate 8 bf16 channels packed in a uint4 into a[0..7]
__device__ __forceinline__ void acc8(uint4 v, float* a) {
    union { unsigned u; float f; } c;
    c.u = v.x << 16;         a[0] += c.f;
    c.u = v.x & 0xffff0000u; a[1] += c.f;
    c.u = v.y << 16;         a[2] += c.f;
    c.u = v.y & 0xffff0000u; a[3] += c.f;
    c.u = v.z << 16;         a[4] += c.f;
    c.u = v.z & 0xffff0000u; a[5] += c.f;
    c.u = v.w << 16;         a[6] += c.f;
    c.u = v.w & 0xffff0000u; a[7] += c.f;
}

// ---------------- init per-(bucket,replica) cursors to fixed-capacity bases ----------------
__global__ void k_init_cur(int* __restrict__ cur) {
    int i = blockIdx.x * blockDim.x + threadIdx.x;
    if (i < NBUCK * NREP) cur[i] = i * BCAPR;
}

// ---------------- pass 1: block-local counting sort -> coalesced bucket-run writes ----------------
__global__ __launch_bounds__(256) void k_bucket(const int* __restrict__ src, const int* __restrict__ dst,
                                                int* __restrict__ cur, unsigned* __restrict__ colp, int e) {
    __shared__ int lh[NBUCK];            // local counts
    __shared__ int lbase[NBUCK];         // local exclusive scan
    __shared__ int lb[NBUCK];            // reserved global base
    __shared__ int sh[256];              // scan temp
    __shared__ unsigned ebuf[EPB];       // 16 KB staged packed edges (bucket-major)
    __shared__ unsigned char ebkt[EPB];  // 4 KB bucket id per staged slot
    int t = threadIdx.x;
    if (t < NBUCK) lh[t] = 0;
    __syncthreads();
    int base = blockIdx.x * EPB + t * 16;
    int bk[16]; int rk[16]; unsigned pk[16];
    if (base + 15 < e) {
        union { int4 v4[4]; int v[16]; } D, S;
        const int4* d4 = reinterpret_cast<const int4*>(dst + base);
        const int4* s4 = reinterpret_cast<const int4*>(src + base);
        D.v4[0] = d4[0]; D.v4[1] = d4[1]; D.v4[2] = d4[2]; D.v4[3] = d4[3];
        S.v4[0] = s4[0]; S.v4[1] = s4[1]; S.v4[2] = s4[2]; S.v4[3] = s4[3];
#pragma unroll
        for (int j = 0; j < 16; ++j) {
            int d = D.v[j];
            bk[j] = d >> BSHIFT;
            pk[j] = ((unsigned)(d & (BNODES - 1)) << 17) | (unsigned)S.v[j];
            rk[j] = atomicAdd(&lh[bk[j]], 1);
        }
    } else {
#pragma unroll
        for (int j = 0; j < 16; ++j) {
            int idx = base + j;
            if (idx < e) {
                int d = dst[idx];
                bk[j] = d >> BSHIFT;
                pk[j] = ((unsigned)(d & (BNODES - 1)) << 17) | (unsigned)src[idx];
                rk[j] = atomicAdd(&lh[bk[j]], 1);
            } else bk[j] = -1;
        }
    }
    __syncthreads();
    // exclusive scan of lh -> lbase; total in sh[255]
    int v = (t < NBUCK) ? lh[t] : 0;
    sh[t] = v;
    __syncthreads();
    for (int off = 1; off < 256; off <<= 1) {
        int x = (t >= off) ? sh[t - off] : 0;
        __syncthreads();
        sh[t] += x;
        __syncthreads();
    }
    if (t < NBUCK) lbase[t] = sh[t] - v;
    // reserve space in this block's replica region
    int rep = blockIdx.x & (NREP - 1);
    if (t < NBUCK) lb[t] = v ? atomicAdd(&cur[t * NREP + rep], v) : 0;
    // stage edges into LDS bucket-major
#pragma unroll
    for (int j = 0; j < 16; ++j) {
        if (bk[j] >= 0) {
            int pos = lbase[bk[j]] + rk[j];
            ebuf[pos] = pk[j];
            ebkt[pos] = (unsigned char)bk[j];
        }
    }
    __syncthreads();
    int tot = sh[255];
    // coalesced copy-out: consecutive i -> consecutive addresses within each run
    for (int i = t; i < tot; i += 256) {
        int b = ebkt[i];
        colp[lb[b] + (i - lbase[b])] = ebuf[i];
    }
}

// ---------------- pass 2: per-bucket counting sort over 8 replica regions -> CSR ----------------
__global__ __launch_bounds__(1024) void k_build(const unsigned* __restrict__ colp, const int* __restrict__ cur,
                                                int* __restrict__ col, int* __restrict__ row_ptr,
                                                int* __restrict__ deg, float* __restrict__ dinv) {
    __shared__ int cnt[BNODES];
    __shared__ int sc[BNODES];
    __shared__ int ex[BNODES];
    __shared__ int curl[BNODES];
    int b = blockIdx.x, t = threadIdx.x;
    if (t < BNODES) cnt[t] = 0;
    __syncthreads();
    int rb[NREP], mr[NREP];
#pragma unroll
    for (int r = 0; r < NREP; ++r) {
        rb[r] = (b * NREP + r) * BCAPR;
        mr[r] = cur[b * NREP + r] - rb[r];
    }
    // count phase: 4 regions interleaved for MLP
#pragma unroll
    for (int r = 0; r < NREP; r += 4) {
        int i0 = t, i1 = t, i2 = t, i3 = t;
        for (;;) {
            bool a0 = i0 < mr[r], a1 = i1 < mr[r + 1], a2 = i2 < mr[r + 2], a3 = i3 < mr[r + 3];
            if (!(a0 | a1 | a2 | a3)) break;
            unsigned p0 = a0 ? colp[rb[r] + i0] : 0;
            unsigned p1 = a1 ? colp[rb[r + 1] + i1] : 0;
            unsigned p2 = a2 ? colp[rb[r + 2] + i2] : 0;
            unsigned p3 = a3 ? colp[rb[r + 3] + i3] : 0;
            if (a0) atomicAdd(&cnt[p0 >> 17], 1);
            if (a1) atomicAdd(&cnt[p1 >> 17], 1);
            if (a2) atomicAdd(&cnt[p2 >> 17], 1);
            if (a3) atomicAdd(&cnt[p3 >> 17], 1);
            i0 += 1024; i1 += 1024; i2 += 1024; i3 += 1024;
        }
    }
    __syncthreads();
    int v = 0;
    if (t < BNODES) { v = cnt[t]; sc[t] = v; }
    __syncthreads();
    for (int off = 1; off < BNODES; off <<= 1) {
        int x = 0;
        if (t < BNODES && t >= off) x = sc[t - off];
        __syncthreads();
        if (t < BNODES) sc[t] += x;
        __syncthreads();
    }
    int colbase = b * BCAPB;
    if (t < BNODES) {
        ex[t] = sc[t] - v;
        curl[t] = 0;
        int node = b * BNODES + t;
        if (node < N_NODES) {
            row_ptr[node] = colbase + ex[t];
            deg[node] = v;
            dinv[node] = rsqrtf((float)v + 1.0f);
        }
    }
    __syncthreads();
    // scatter phase: 2 regions interleaved
#pragma unroll
    for (int r = 0; r < NREP; r += 2) {
        int i0 = t, i1 = t;
        for (;;) {
            bool a0 = i0 < mr[r], a1 = i1 < mr[r + 1];
            if (!a0 && !a1) break;
            unsigned p0 = a0 ? colp[rb[r] + i0] : 0;
            unsigned p1 = a1 ? colp[rb[r + 1] + i1] : 0;
            if (a0) {
                int l = p0 >> 17;
                int pp = atomicAdd(&curl[l], 1);
                col[colbase + ex[l] + pp] = (int)(p0 & 0x1FFFF);
            }
            if (a1) {
                int l = p1 >> 17;
                int pp = atomicAdd(&curl[l], 1);
                col[colbase + ex[l] + pp] = (int)(p1 & 0x1FFFF);
            }
            i0 += 1024; i1 += 1024;
        }
    }
}

// ---------------- h1' = bf16( dinv * (x @ W1) ), 32-row tile, b128 LDS reads ----------------
__global__ __launch_bounds__(256) void k_gemm1(const float* __restrict__ x,
                                               const float* __restrict__ W1,
                                               const float* __restrict__ dinv,
                                               unsigned short* __restrict__ h1p, int n) {
    __shared__ float Wt[HID * XP];     // W transposed: Wt[c][k], 8.4 KB
    __shared__ float xs[TR * XP];      // x tile, 16.9 KB
    int t = threadIdx.x;
    for (int i = t; i < HID * IN_CH; i += 256) {
        int k = i & 127, c = i >> 7;
        Wt[c * XP + k] = W1[k * HID + c];
    }
    int row0 = blockIdx.x * TR;
    for (int i = t; i < TR * IN_CH / 4; i += 256) {
        int r = i >> 5, c4 = i & 31;
        int row = row0 + r;
        float4 v = (row < n) ? reinterpret_cast<const float4*>(x)[(size_t)row * 32 + c4]
                             : make_float4(0.f, 0.f, 0.f, 0.f);
        *reinterpret_cast<float4*>(&xs[r * XP + c4 * 4]) = v;
    }
    __syncthreads();
    int r = t >> 4;    // 0..15 -> rows r, r+16
    int c = t & 15;
    const float4* xr0 = reinterpret_cast<const float4*>(&xs[r * XP]);
    const float4* xr1 = reinterpret_cast<const float4*>(&xs[(r + 16) * XP]);
    const float4* wc  = reinterpret_cast<const float4*>(&Wt[c * XP]);
    float a0 = 0.f, a1 = 0.f;
#pragma unroll 4
    for (int k4 = 0; k4 < IN_CH / 4; ++k4) {
        float4 wv  = wc[k4];
        float4 v0  = xr0[k4];
        float4 v1  = xr1[k4];
        a0 = fmaf(v0.x, wv.x, a0); a0 = fmaf(v0.y, wv.y, a0);
        a0 = fmaf(v0.z, wv.z, a0); a0 = fmaf(v0.w, wv.w, a0);
        a1 = fmaf(v1.x, wv.x, a1); a1 = fmaf(v1.y, wv.y, a1);
        a1 = fmaf(v1.z, wv.z, a1); a1 = fmaf(v1.w, wv.w, a1);
    }
    int rr0 = row0 + r, rr1 = rr0 + 16;
    if (rr0 < n) h1p[(size_t)rr0 * HID + c] = f2bf(dinv[rr0] * a0);
    if (rr1 < n) h1p[(size_t)rr1 * HID + c] = f2bf(dinv[rr1] * a1);
}

// ---------------- gather layer 1: 8 threads/node, 8-deep load batching ----------------
__global__ __launch_bounds__(256) void k_gather1(const unsigned short* __restrict__ h1p,
                                                 const int* __restrict__ row_ptr,
                                                 const int* __restrict__ deg,
                                                 const float* __restrict__ dinv,
                                                 const int* __restrict__ col,
                                                 const float* __restrict__ b1,
                                                 unsigned short* __restrict__ h2p, int n) {
    int t = blockIdx.x * blockDim.x + threadIdx.x;
    int i = t >> 3;
    if (i >= n) return;
    int q = t & 1, p = (t >> 1) & 3;
    const uint4* hp = reinterpret_cast<const uint4*>(h1p);
    float a[8] = {0, 0, 0, 0, 0, 0, 0, 0};
    int j0 = row_ptr[i], j1 = j0 + deg[i];
    int j = j0 + p;
    for (; j + 28 < j1; j += 32) {   // 8 edges in flight (covers mean degree in one iter)
        int s0 = col[j],      s1 = col[j + 4],  s2 = col[j + 8],  s3 = col[j + 12];
        int s4 = col[j + 16], s5 = col[j + 20], s6 = col[j + 24], s7 = col[j + 28];
        uint4 v0 = hp[(size_t)s0 * 2 + q];
        uint4 v1 = hp[(size_t)s1 * 2 + q];
        uint4 v2 = hp[(size_t)s2 * 2 + q];
        uint4 v3 = hp[(size_t)s3 * 2 + q];
        uint4 v4 = hp[(size_t)s4 * 2 + q];
        uint4 v5 = hp[(size_t)s5 * 2 + q];
        uint4 v6 = hp[(size_t)s6 * 2 + q];
        uint4 v7 = hp[(size_t)s7 * 2 + q];
        acc8(v0, a); acc8(v1, a); acc8(v2, a); acc8(v3, a);
        acc8(v4, a); acc8(v5, a); acc8(v6, a); acc8(v7, a);
    }
    for (; j + 12 < j1; j += 16) {
        int s0 = col[j], s1 = col[j + 4], s2 = col[j + 8], s3 = col[j + 12];
        uint4 v0 = hp[(size_t)s0 * 2 + q];
        uint4 v1 = hp[(size_t)s1 * 2 + q];
        uint4 v2 = hp[(size_t)s2 * 2 + q];
        uint4 v3 = hp[(size_t)s3 * 2 + q];
        acc8(v0, a); acc8(v1, a); acc8(v2, a); acc8(v3, a);
    }
    for (; j < j1; j += 4) acc8(hp[(size_t)col[j] * 2 + q], a);
    // combine edge-quarter partners (lanes ^2 and ^4 share node i and q)
#pragma unroll
    for (int k = 0; k < 8; ++k) {
        a[k] += __shfl_xor(a[k], 2);
        a[k] += __shfl_xor(a[k], 4);
    }
    if (p == 0) {
        acc8(hp[(size_t)i * 2 + q], a);   // self-loop
        float di = dinv[i];
        float4 bl = *reinterpret_cast<const float4*>(&b1[q * 8]);
        float4 bh = *reinterpret_cast<const float4*>(&b1[q * 8 + 4]);
        float o[8];
        o[0] = di * fmaxf(fmaf(di, a[0], bl.x), 0.f);
        o[1] = di * fmaxf(fmaf(di, a[1], bl.y), 0.f);
        o[2] = di * fmaxf(fmaf(di, a[2], bl.z), 0.f);
        o[3] = di * fmaxf(fmaf(di, a[3], bl.w), 0.f);
        o[4] = di * fmaxf(fmaf(di, a[4], bh.x), 0.f);
        o[5] = di * fmaxf(fmaf(di, a[5], bh.y), 0.f);
        o[6] = di * fmaxf(fmaf(di, a[6], bh.z), 0.f);
        o[7] = di * fmaxf(fmaf(di, a[7], bh.w), 0.f);
        uint4 ov;
        ov.x = pack2(o[0], o[1]);
        ov.y = pack2(o[2], o[3]);
        ov.z = pack2(o[4], o[5]);
        ov.w = pack2(o[6], o[7]);
        reinterpret_cast<uint4*>(h2p)[(size_t)i * 2 + q] = ov;
    }
}

// ---------------- gather layer 2: 8 threads/node, 8-deep batching + fused 16x64 GEMM ----------------
__global__ __launch_bounds__(256) void k_gather2_out(const unsigned short* __restrict__ h2p,
                                                     const int* __restrict__ row_ptr,
                                                     const int* __restrict__ deg,
                                                     const float* __restrict__ dinv,
                                                     const int* __restrict__ col,
                                                     const float* __restrict__ W2,
                                                     const float* __restrict__ b2,
                                                     float* __restrict__ out, int n) {
    __shared__ float Ws[HID * OUT_CH];    // 4 KB
    __shared__ float as[32][HID + 1];     // 2.2 KB
    int t = threadIdx.x;
    for (int i = t; i < HID * OUT_CH; i += 256) Ws[i] = W2[i];
    int nl = t >> 3;                       // 32 nodes/block
    int i = blockIdx.x * 32 + nl;
    int q = t & 1, p = (t >> 1) & 3;
    const uint4* hp = reinterpret_cast<const uint4*>(h2p);
    if (i < n) {
        float a[8] = {0, 0, 0, 0, 0, 0, 0, 0};
        int j0 = row_ptr[i], j1 = j0 + deg[i];
        int j = j0 + p;
        for (; j + 28 < j1; j += 32) {
            int s0 = col[j],      s1 = col[j + 4],  s2 = col[j + 8],  s3 = col[j + 12];
            int s4 = col[j + 16], s5 = col[j + 20], s6 = col[j + 24], s7 = col[j + 28];
            uint4 v0 = hp[(size_t)s0 * 2 + q];
            uint4 v1 = hp[(size_t)s1 * 2 + q];
            uint4 v2 = hp[(size_t)s2 * 2 + q];
            uint4 v3 = hp[(size_t)s3 * 2 + q];
            uint4 v4 = hp[(size_t)s4 * 2 + q];
            uint4 v5 = hp[(size_t)s5 * 2 + q];
            uint4 v6 = hp[(size_t)s6 * 2 + q];
            uint4 v7 = hp[(size_t)s7 * 2 + q];
            acc8(v0, a); acc8(v1, a); acc8(v2, a); acc8(v3, a);
            acc8(v4, a); acc8(v5, a); acc8(v6, a); acc8(v7, a);
        }
        for (; j + 12 < j1; j += 16) {
            int s0 = col[j], s1 = col[j + 4], s2 = col[j + 8], s3 = col[j + 12];
            uint4 v0 = hp[(size_t)s0 * 2 + q];
            uint4 v1 = hp[(size_t)s1 * 2 + q];
            uint4 v2 = hp[(size_t)s2 * 2 + q];
            uint4 v3 = hp[(size_t)s3 * 2 + q];
            acc8(v0, a); acc8(v1, a); acc8(v2, a); acc8(v3, a);
        }
        for (; j < j1; j += 4) acc8(hp[(size_t)col[j] * 2 + q], a);
#pragma unroll
        for (int k = 0; k < 8; ++k) {
            a[k] += __shfl_xor(a[k], 2);
            a[k] += __shfl_xor(a[k], 4);
        }
        if (p == 0) {
            acc8(hp[(size_t)i * 2 + q], a);   // self
            float di = dinv[i];
#pragma unroll
            for (int k = 0; k < 8; ++k) as[nl][q * 8 + k] = di * a[k];
        }
    } else if (p == 0) {
#pragma unroll
        for (int k = 0; k < 8; ++k) as[nl][q * 8 + k] = 0.f;
    }
    __syncthreads();
    // epilogue: node nl, cols g*8 .. g*8+7
    int g = t & 7;
    float r[8];
#pragma unroll
    for (int c = 0; c < 8; ++c) r[c] = b2[g * 8 + c];
#pragma unroll
    for (int k = 0; k < HID; ++k) {
        float a = as[nl][k];
#pragma unroll
        for (int c = 0; c < 8; ++c) r[c] = fmaf(a, Ws[k * OUT_CH + g * 8 + c], r[c]);
    }
    if (i < n) {
        float* op = &out[(size_t)i * OUT_CH + g * 8];
        *reinterpret_cast<float4*>(&op[0]) = make_float4(r[0], r[1], r[2], r[3]);
        *reinterpret_cast<float4*>(&op[4]) = make_float4(r[4], r[5], r[6], r[7]);
    }
}

extern "C" void kernel_launch(void* const* d_in, const int* in_sizes, int n_in,
                              void* d_out, int out_size, void* d_ws, size_t ws_size,
                              hipStream_t stream) {
    const float* x  = (const float*)d_in[0];
    const int*   ei = (const int*)d_in[1];
    const float* W1 = (const float*)d_in[2];
    const float* b1 = (const float*)d_in[3];
    const float* W2 = (const float*)d_in[4];
    const float* b2 = (const float*)d_in[5];
    float* out = (float*)d_out;

    const int* src = ei;
    const int* dst = ei + N_EDGES;

    // workspace layout (4B units)
    int*            cur     = (int*)d_ws;                          // [0, 1600)       1568 cursors
    int*            row_ptr = cur + 1600;                          // [1600, 101600)
    int*            deg     = row_ptr + N_NODES;                   // [101600, 201600)
    float*          dinv    = (float*)(deg + N_NODES);             // [201600, 301600)
    int*            col     = (int*)(dinv + N_NODES);              // [301600, 3914272)  196*18432
    unsigned short* h1p     = (unsigned short*)(col + NBUCK * BCAPB);  // [3914272, 4714272) bf16 N*16
    unsigned*       colp    = (unsigned*)((int*)h1p + 800000);     // [4714272, 8326944)  196*8*2304
    unsigned short* h2p     = (unsigned short*)colp;               // aliases colp (dead after k_build)

    // bucketed edge list: block-local counting sort, per-replica regions
    k_init_cur<<<(NBUCK * NREP + 255) / 256, 256, 0, stream>>>(cur);
    k_bucket<<<(N_EDGES + EPB - 1) / EPB, 256, 0, stream>>>(src, dst, cur, colp, N_EDGES);
    // per-bucket counting sort over replica regions -> full CSR + degrees + dinv
    k_build<<<NBUCK, 1024, 0, stream>>>(colp, cur, col, row_ptr, deg, dinv);

    // h1' = bf16(dinv * (x @ W1))
    k_gemm1<<<(N_NODES + TR - 1) / TR, 256, 0, stream>>>(x, W1, dinv, h1p, N_NODES);

    // layer 1: gather + bias + relu + pre-scale  (h2p aliases colp region; colp dead after k_build)
    k_gather1<<<((size_t)8 * N_NODES + 255) / 256, 256, 0, stream>>>(h1p, row_ptr, deg, dinv, col,
                                                                     b1, h2p, N_NODES);

    // layer 2: gather fused with final GEMM + bias
    k_gather2_out<<<(N_NODES + 31) / 32, 256, 0, stream>>>(h2p, row_ptr, deg, dinv, col, W2, b2,
                                                           out, N_NODES);
}

// Round 17
// 136.294 us; speedup vs baseline: 1.0401x; 1.0401x over previous
//
#include <hip/hip_runtime.h>
#include <hip/hip_bf16.h>

#define N_NODES 100000
#define N_EDGES 3200000
#define IN_CH 128
#define HID 16
#define OUT_CH 64
#define BSHIFT 9
#define BNODES 512              // nodes per bucket
#define NBUCK 196               // ceil(100000/512)
#define NREP 8                  // cursor/region replicas (~ per-XCD under round-robin dispatch)
#define BCAPR 2304              // per-(bucket,replica) colp capacity (mean 2048 + ~5.7 sigma)
#define BCAPB (NREP * BCAPR)    // 18432 col words per bucket
#define TR 32                   // gemm1 rows per block
#define XP 132                  // padded LDS row stride (keeps 16B align)
#define EPB 4096                // k_bucket edges per block

__device__ __forceinline__ unsigned short f2bf(float f) {
    union { float f; unsigned v; } t; t.f = f;
    unsigned r = t.v + 0x7FFFu + ((t.v >> 16) & 1u);   // round-to-nearest-even
    return (unsigned short)(r >> 16);
}
__device__ __forceinline__ unsigned pack2(float lo, float hi) {
    return (unsigned)f2bf(lo) | ((unsigned)f2bf(hi) << 16);
}
// accumulate 8 bf16 channels packed in a uint4 into a[0..7]
__device__ __forceinline__ void acc8(uint4 v, float* a) {
    union { unsigned u; float f; } c;
    c.u = v.x << 16;         a[0] += c.f;
    c.u = v.x & 0xffff0000u; a[1] += c.f;
    c.u = v.y << 16;         a[2] += c.f;
    c.u = v.y & 0xffff0000u; a[3] += c.f;
    c.u = v.z << 16;         a[4] += c.f;
    c.u = v.z & 0xffff0000u; a[5] += c.f;
    c.u = v.w << 16;         a[6] += c.f;
    c.u = v.w & 0xffff0000u; a[7] += c.f;
}

// ---------------- init per-(bucket,replica) cursors to fixed-capacity bases ----------------
__global__ void k_init_cur(int* __restrict__ cur) {
    int i = blockIdx.x * blockDim.x + threadIdx.x;
    if (i < NBUCK * NREP) cur[i] = i * BCAPR;
}

// ---------------- pass 1: block-local counting sort -> coalesced bucket-run writes ----------------
__global__ __launch_bounds__(256) void k_bucket(const int* __restrict__ src, const int* __restrict__ dst,
                                                int* __restrict__ cur, unsigned* __restrict__ colp, int e) {
    __shared__ int lh[NBUCK];            // local counts
    __shared__ int lbase[NBUCK];         // local exclusive scan
    __shared__ int lb[NBUCK];            // reserved global base
    __shared__ int sh[256];              // scan temp
    __shared__ unsigned ebuf[EPB];       // 16 KB staged packed edges (bucket-major)
    __shared__ unsigned char ebkt[EPB];  // 4 KB bucket id per staged slot
    int t = threadIdx.x;
    if (t < NBUCK) lh[t] = 0;
    __syncthreads();
    int base = blockIdx.x * EPB + t * 16;
    int bk[16]; int rk[16]; unsigned pk[16];
    if (base + 15 < e) {
        union { int4 v4[4]; int v[16]; } D, S;
        const int4* d4 = reinterpret_cast<const int4*>(dst + base);
        const int4* s4 = reinterpret_cast<const int4*>(src + base);
        D.v4[0] = d4[0]; D.v4[1] = d4[1]; D.v4[2] = d4[2]; D.v4[3] = d4[3];
        S.v4[0] = s4[0]; S.v4[1] = s4[1]; S.v4[2] = s4[2]; S.v4[3] = s4[3];
#pragma unroll
        for (int j = 0; j < 16; ++j) {
            int d = D.v[j];
            bk[j] = d >> BSHIFT;
            pk[j] = ((unsigned)(d & (BNODES - 1)) << 17) | (unsigned)S.v[j];
            rk[j] = atomicAdd(&lh[bk[j]], 1);
        }
    } else {
#pragma unroll
        for (int j = 0; j < 16; ++j) {
            int idx = base + j;
            if (idx < e) {
                int d = dst[idx];
                bk[j] = d >> BSHIFT;
                pk[j] = ((unsigned)(d & (BNODES - 1)) << 17) | (unsigned)src[idx];
                rk[j] = atomicAdd(&lh[bk[j]], 1);
            } else bk[j] = -1;
        }
    }
    __syncthreads();
    // exclusive scan of lh -> lbase; total in sh[255]
    int v = (t < NBUCK) ? lh[t] : 0;
    sh[t] = v;
    __syncthreads();
    for (int off = 1; off < 256; off <<= 1) {
        int x = (t >= off) ? sh[t - off] : 0;
        __syncthreads();
        sh[t] += x;
        __syncthreads();
    }
    if (t < NBUCK) lbase[t] = sh[t] - v;
    // reserve space in this block's replica region
    int rep = blockIdx.x & (NREP - 1);
    if (t < NBUCK) lb[t] = v ? atomicAdd(&cur[t * NREP + rep], v) : 0;
    // stage edges into LDS bucket-major
#pragma unroll
    for (int j = 0; j < 16; ++j) {
        if (bk[j] >= 0) {
            int pos = lbase[bk[j]] + rk[j];
            ebuf[pos] = pk[j];
            ebkt[pos] = (unsigned char)bk[j];
        }
    }
    __syncthreads();
    int tot = sh[255];
    // coalesced copy-out: consecutive i -> consecutive addresses within each run
    for (int i = t; i < tot; i += 256) {
        int b = ebkt[i];
        colp[lb[b] + (i - lbase[b])] = ebuf[i];
    }
}

// ---------------- pass 2: per-bucket counting sort, SINGLE global pass (LDS edge staging) ----------------
// Whole bucket (<=18432 packed edges = 73.7 KB) staged in LDS while counting; scatter reads LDS.
__global__ __launch_bounds__(1024) void k_build(const unsigned* __restrict__ colp, const int* __restrict__ cur,
                                                int* __restrict__ col, int* __restrict__ row_ptr,
                                                int* __restrict__ deg, float* __restrict__ dinv) {
    __shared__ unsigned ebuf[BCAPB];   // 73.7 KB staged packed edges
    __shared__ int cnt[BNODES];
    __shared__ int sc[BNODES];
    __shared__ int ex[BNODES];
    __shared__ int curl[BNODES];
    int b = blockIdx.x, t = threadIdx.x;
    if (t < BNODES) cnt[t] = 0;
    __syncthreads();
    int rb[NREP], mr[NREP], ofs[NREP];
    int m = 0;
#pragma unroll
    for (int r = 0; r < NREP; ++r) {
        rb[r] = (b * NREP + r) * BCAPR;
        mr[r] = cur[b * NREP + r] - rb[r];
        ofs[r] = m;
        m += mr[r];
    }
    // single global read: stream 4 regions interleaved into LDS while counting
#pragma unroll
    for (int r = 0; r < NREP; r += 4) {
        int i0 = t, i1 = t, i2 = t, i3 = t;
        for (;;) {
            bool a0 = i0 < mr[r], a1 = i1 < mr[r + 1], a2 = i2 < mr[r + 2], a3 = i3 < mr[r + 3];
            if (!(a0 | a1 | a2 | a3)) break;
            unsigned p0 = a0 ? colp[rb[r] + i0] : 0;
            unsigned p1 = a1 ? colp[rb[r + 1] + i1] : 0;
            unsigned p2 = a2 ? colp[rb[r + 2] + i2] : 0;
            unsigned p3 = a3 ? colp[rb[r + 3] + i3] : 0;
            if (a0) { ebuf[ofs[r] + i0] = p0;     atomicAdd(&cnt[p0 >> 17], 1); }
            if (a1) { ebuf[ofs[r + 1] + i1] = p1; atomicAdd(&cnt[p1 >> 17], 1); }
            if (a2) { ebuf[ofs[r + 2] + i2] = p2; atomicAdd(&cnt[p2 >> 17], 1); }
            if (a3) { ebuf[ofs[r + 3] + i3] = p3; atomicAdd(&cnt[p3 >> 17], 1); }
            i0 += 1024; i1 += 1024; i2 += 1024; i3 += 1024;
        }
    }
    __syncthreads();
    int v = 0;
    if (t < BNODES) { v = cnt[t]; sc[t] = v; }
    __syncthreads();
    for (int off = 1; off < BNODES; off <<= 1) {
        int x = 0;
        if (t < BNODES && t >= off) x = sc[t - off];
        __syncthreads();
        if (t < BNODES) sc[t] += x;
        __syncthreads();
    }
    int colbase = b * BCAPB;
    if (t < BNODES) {
        ex[t] = sc[t] - v;
        curl[t] = 0;
        int node = b * BNODES + t;
        if (node < N_NODES) {
            row_ptr[node] = colbase + ex[t];
            deg[node] = v;
            dinv[node] = rsqrtf((float)v + 1.0f);
        }
    }
    __syncthreads();
    // scatter from LDS (no second global read)
    for (int i = t; i < m; i += 1024) {
        unsigned pv = ebuf[i];
        int l = pv >> 17;
        int pp = atomicAdd(&curl[l], 1);
        col[colbase + ex[l] + pp] = (int)(pv & 0x1FFFF);
    }
}

// ---------------- h1' = bf16( dinv * (x @ W1) ), 32-row tile, b128 LDS reads ----------------
__global__ __launch_bounds__(256) void k_gemm1(const float* __restrict__ x,
                                               const float* __restrict__ W1,
                                               const float* __restrict__ dinv,
                                               unsigned short* __restrict__ h1p, int n) {
    __shared__ float Wt[HID * XP];     // W transposed: Wt[c][k], 8.4 KB
    __shared__ float xs[TR * XP];      // x tile, 16.9 KB
    int t = threadIdx.x;
    for (int i = t; i < HID * IN_CH; i += 256) {
        int k = i & 127, c = i >> 7;
        Wt[c * XP + k] = W1[k * HID + c];
    }
    int row0 = blockIdx.x * TR;
    for (int i = t; i < TR * IN_CH / 4; i += 256) {
        int r = i >> 5, c4 = i & 31;
        int row = row0 + r;
        float4 v = (row < n) ? reinterpret_cast<const float4*>(x)[(size_t)row * 32 + c4]
                             : make_float4(0.f, 0.f, 0.f, 0.f);
        *reinterpret_cast<float4*>(&xs[r * XP + c4 * 4]) = v;
    }
    __syncthreads();
    int r = t >> 4;    // 0..15 -> rows r, r+16
    int c = t & 15;
    const float4* xr0 = reinterpret_cast<const float4*>(&xs[r * XP]);
    const float4* xr1 = reinterpret_cast<const float4*>(&xs[(r + 16) * XP]);
    const float4* wc  = reinterpret_cast<const float4*>(&Wt[c * XP]);
    float a0 = 0.f, a1 = 0.f;
#pragma unroll 4
    for (int k4 = 0; k4 < IN_CH / 4; ++k4) {
        float4 wv  = wc[k4];
        float4 v0  = xr0[k4];
        float4 v1  = xr1[k4];
        a0 = fmaf(v0.x, wv.x, a0); a0 = fmaf(v0.y, wv.y, a0);
        a0 = fmaf(v0.z, wv.z, a0); a0 = fmaf(v0.w, wv.w, a0);
        a1 = fmaf(v1.x, wv.x, a1); a1 = fmaf(v1.y, wv.y, a1);
        a1 = fmaf(v1.z, wv.z, a1); a1 = fmaf(v1.w, wv.w, a1);
    }
    int rr0 = row0 + r, rr1 = rr0 + 16;
    if (rr0 < n) h1p[(size_t)rr0 * HID + c] = f2bf(dinv[rr0] * a0);
    if (rr1 < n) h1p[(size_t)rr1 * HID + c] = f2bf(dinv[rr1] * a1);
}

// ---------------- gather layer 1: 8 threads/node (q=ch-half, p=edge-quarter), shfl combine ----------------
__global__ __launch_bounds__(256) void k_gather1(const unsigned short* __restrict__ h1p,
                                                 const int* __restrict__ row_ptr,
                                                 const int* __restrict__ deg,
                                                 const float* __restrict__ dinv,
                                                 const int* __restrict__ col,
                                                 const float* __restrict__ b1,
                                                 unsigned short* __restrict__ h2p, int n) {
    int t = blockIdx.x * blockDim.x + threadIdx.x;
    int i = t >> 3;
    if (i >= n) return;
    int q = t & 1, p = (t >> 1) & 3;
    const uint4* hp = reinterpret_cast<const uint4*>(h1p);
    float a[8] = {0, 0, 0, 0, 0, 0, 0, 0};
    int j0 = row_ptr[i], j1 = j0 + deg[i];
    int j = j0 + p;
    for (; j + 12 < j1; j += 16) {
        int s0 = col[j], s1 = col[j + 4], s2 = col[j + 8], s3 = col[j + 12];
        uint4 v0 = hp[(size_t)s0 * 2 + q];
        uint4 v1 = hp[(size_t)s1 * 2 + q];
        uint4 v2 = hp[(size_t)s2 * 2 + q];
        uint4 v3 = hp[(size_t)s3 * 2 + q];
        acc8(v0, a); acc8(v1, a); acc8(v2, a); acc8(v3, a);
    }
    for (; j < j1; j += 4) acc8(hp[(size_t)col[j] * 2 + q], a);
    // combine edge-quarter partners (lanes ^2 and ^4 share node i and q)
#pragma unroll
    for (int k = 0; k < 8; ++k) {
        a[k] += __shfl_xor(a[k], 2);
        a[k] += __shfl_xor(a[k], 4);
    }
    if (p == 0) {
        acc8(hp[(size_t)i * 2 + q], a);   // self-loop
        float di = dinv[i];
        float4 bl = *reinterpret_cast<const float4*>(&b1[q * 8]);
        float4 bh = *reinterpret_cast<const float4*>(&b1[q * 8 + 4]);
        float o[8];
        o[0] = di * fmaxf(fmaf(di, a[0], bl.x), 0.f);
        o[1] = di * fmaxf(fmaf(di, a[1], bl.y), 0.f);
        o[2] = di * fmaxf(fmaf(di, a[2], bl.z), 0.f);
        o[3] = di * fmaxf(fmaf(di, a[3], bl.w), 0.f);
        o[4] = di * fmaxf(fmaf(di, a[4], bh.x), 0.f);
        o[5] = di * fmaxf(fmaf(di, a[5], bh.y), 0.f);
        o[6] = di * fmaxf(fmaf(di, a[6], bh.z), 0.f);
        o[7] = di * fmaxf(fmaf(di, a[7], bh.w), 0.f);
        uint4 ov;
        ov.x = pack2(o[0], o[1]);
        ov.y = pack2(o[2], o[3]);
        ov.z = pack2(o[4], o[5]);
        ov.w = pack2(o[6], o[7]);
        reinterpret_cast<uint4*>(h2p)[(size_t)i * 2 + q] = ov;
    }
}

// ---------------- gather layer 2: 8 threads/node (32 nodes/block) + fused 16x64 GEMM + b2 ----------------
__global__ __launch_bounds__(256) void k_gather2_out(const unsigned short* __restrict__ h2p,
                                                     const int* __restrict__ row_ptr,
                                                     const int* __restrict__ deg,
                                                     const float* __restrict__ dinv,
                                                     const int* __restrict__ col,
                                                     const float* __restrict__ W2,
                                                     const float* __restrict__ b2,
                                                     float* __restrict__ out, int n) {
    __shared__ float Ws[HID * OUT_CH];    // 4 KB
    __shared__ float as[32][HID + 1];     // 2.2 KB
    int t = threadIdx.x;
    for (int i = t; i < HID * OUT_CH; i += 256) Ws[i] = W2[i];
    int nl = t >> 3;                       // 32 nodes/block
    int i = blockIdx.x * 32 + nl;
    int q = t & 1, p = (t >> 1) & 3;
    const uint4* hp = reinterpret_cast<const uint4*>(h2p);
    if (i < n) {
        float a[8] = {0, 0, 0, 0, 0, 0, 0, 0};
        int j0 = row_ptr[i], j1 = j0 + deg[i];
        int j = j0 + p;
        for (; j + 12 < j1; j += 16) {
            int s0 = col[j], s1 = col[j + 4], s2 = col[j + 8], s3 = col[j + 12];
            uint4 v0 = hp[(size_t)s0 * 2 + q];
            uint4 v1 = hp[(size_t)s1 * 2 + q];
            uint4 v2 = hp[(size_t)s2 * 2 + q];
            uint4 v3 = hp[(size_t)s3 * 2 + q];
            acc8(v0, a); acc8(v1, a); acc8(v2, a); acc8(v3, a);
        }
        for (; j < j1; j += 4) acc8(hp[(size_t)col[j] * 2 + q], a);
#pragma unroll
        for (int k = 0; k < 8; ++k) {
            a[k] += __shfl_xor(a[k], 2);
            a[k] += __shfl_xor(a[k], 4);
        }
        if (p == 0) {
            acc8(hp[(size_t)i * 2 + q], a);   // self
            float di = dinv[i];
#pragma unroll
            for (int k = 0; k < 8; ++k) as[nl][q * 8 + k] = di * a[k];
        }
    } else if (p == 0) {
#pragma unroll
        for (int k = 0; k < 8; ++k) as[nl][q * 8 + k] = 0.f;
    }
    __syncthreads();
    // epilogue: node nl, cols g*8 .. g*8+7
    int g = t & 7;
    float r[8];
#pragma unroll
    for (int c = 0; c < 8; ++c) r[c] = b2[g * 8 + c];
#pragma unroll
    for (int k = 0; k < HID; ++k) {
        float a = as[nl][k];
#pragma unroll
        for (int c = 0; c < 8; ++c) r[c] = fmaf(a, Ws[k * OUT_CH + g * 8 + c], r[c]);
    }
    if (i < n) {
        float* op = &out[(size_t)i * OUT_CH + g * 8];
        *reinterpret_cast<float4*>(&op[0]) = make_float4(r[0], r[1], r[2], r[3]);
        *reinterpret_cast<float4*>(&op[4]) = make_float4(r[4], r[5], r[6], r[7]);
    }
}

extern "C" void kernel_launch(void* const* d_in, const int* in_sizes, int n_in,
                              void* d_out, int out_size, void* d_ws, size_t ws_size,
                              hipStream_t stream) {
    const float* x  = (const float*)d_in[0];
    const int*   ei = (const int*)d_in[1];
    const float* W1 = (const float*)d_in[2];
    const float* b1 = (const float*)d_in[3];
    const float* W2 = (const float*)d_in[4];
    const float* b2 = (const float*)d_in[5];
    float* out = (float*)d_out;

    const int* src = ei;
    const int* dst = ei + N_EDGES;

    // workspace layout (4B units)
    int*            cur     = (int*)d_ws;                          // [0, 1600)       1568 cursors
    int*            row_ptr = cur + 1600;                          // [1600, 101600)
    int*            deg     = row_ptr + N_NODES;                   // [101600, 201600)
    float*          dinv    = (float*)(deg + N_NODES);             // [201600, 301600)
    int*            col     = (int*)(dinv + N_NODES);              // [301600, 3914272)  196*18432
    unsigned short* h1p     = (unsigned short*)(col + NBUCK * BCAPB);  // [3914272, 4714272) bf16 N*16
    unsigned*       colp    = (unsigned*)((int*)h1p + 800000);     // [4714272, 8326944)  196*8*2304
    unsigned short* h2p     = (unsigned short*)colp;               // aliases colp (dead after k_build)

    // bucketed edge list: block-local counting sort, per-replica regions
    k_init_cur<<<(NBUCK * NREP + 255) / 256, 256, 0, stream>>>(cur);
    k_bucket<<<(N_EDGES + EPB - 1) / EPB, 256, 0, stream>>>(src, dst, cur, colp, N_EDGES);
    // per-bucket counting sort (single global pass, LDS staging) -> full CSR + degrees + dinv
    k_build<<<NBUCK, 1024, 0, stream>>>(colp, cur, col, row_ptr, deg, dinv);

    // h1' = bf16(dinv * (x @ W1))
    k_gemm1<<<(N_NODES + TR - 1) / TR, 256, 0, stream>>>(x, W1, dinv, h1p, N_NODES);

    // layer 1: gather + bias + relu + pre-scale  (h2p aliases colp region; colp dead after k_build)
    k_gather1<<<((size_t)8 * N_NODES + 255) / 256, 256, 0, stream>>>(h1p, row_ptr, deg, dinv, col,
                                                                     b1, h2p, N_NODES);

    // layer 2: gather fused with final GEMM + bias
    k_gather2_out<<<(N_NODES + 31) / 32, 256, 0, stream>>>(h2p, row_ptr, deg, dinv, col, W2, b2,
                                                           out, N_NODES);
}